// Round 18
// baseline (145.904 us; speedup 1.0000x reference)
//
#include <hip/hip_runtime.h>
#include <math.h>

#define NB     262144   // batch (tokens)
#define DD     512      // d_routing
#define NG     4        // groups
#define NGS    4        // group size
#define NOUT   20       // 4 group logits + 16 in-group logits

#define TPB    256      // 4 waves/block; 40KB LDS -> 4 blocks/CU = 16 waves
#define TOKS   256      // tokens per block; wave owns 64 = 2 passes x 32

typedef float f32x4 __attribute__((ext_vector_type(4)));

// R17's cooperative-token, x-in-registers scheme with T=4 tokens/lane:
// each w ds_read_b128 (1KB on the LDS return bus regardless of broadcast
// duplication -- the R17 limiter at ~102us/CU) now feeds FMAs for FOUR
// tokens, halving LDS-bus time vs T=2. x loads stay straight-to-VGPR,
// single-touch full lines, no main-loop barriers, 16 free-running waves/CU.
__global__ __launch_bounds__(TPB, 2) void router_k(
    const float* __restrict__ x,        // [NB, DD]
    const float* __restrict__ group_w,  // [NG, DD]
    const float* __restrict__ group_b,  // [NG]
    const float* __restrict__ in_w,     // [NG*NGS, DD]
    const float* __restrict__ in_b,     // [NG, NGS]
    const int*   __restrict__ experts,  // [NG, NGS]
    float*       __restrict__ out)      // [2*NB*2]: indices then weights, fp32
{
    __shared__ float wlds[NOUT * DD];   // 40960B: rows 0..3 gw, 4..19 in_w
    {
        const float4* gw4 = reinterpret_cast<const float4*>(group_w);
        const float4* iw4 = reinterpret_cast<const float4*>(in_w);
        float4* wl4 = reinterpret_cast<float4*>(wlds);
        for (int i = threadIdx.x; i < (NG * DD) / 4; i += TPB)
            wl4[i] = gw4[i];
        for (int i = threadIdx.x; i < (NG * NGS * DD) / 4; i += TPB)
            wl4[(NG * DD) / 4 + i] = iw4[i];
    }
    __syncthreads();   // only barrier in the kernel

    const int tid  = threadIdx.x;
    const int wid  = tid >> 6;
    const int lane = tid & 63;
    const int tg   = lane >> 3;         // token-in-pass base (0..7)
    const int d8   = lane & 7;          // d-slice owner (0..7)
    const int wtok0 = blockIdx.x * TOKS + wid * 64;

    float2* outi = reinterpret_cast<float2*>(out);
    float2* outw = reinterpret_cast<float2*>(out + (size_t)NB * 2);

#pragma unroll 1
    for (int p = 0; p < 2; ++p) {
        const int t0 = wtok0 + p * 32 + tg;   // tokens t0, +8, +16, +24
        const float* xr0 = x + (size_t)t0 * DD + d8 * 4;
        const float* xr1 = xr0 +  8 * DD;
        const float* xr2 = xr0 + 16 * DD;
        const float* xr3 = xr0 + 24 * DD;

        float acc0[NOUT], acc1[NOUT], acc2[NOUT], acc3[NOUT];
#pragma unroll
        for (int o = 0; o < NOUT; ++o) {
            acc0[o] = 0.f; acc1[o] = 0.f; acc2[o] = 0.f; acc3[o] = 0.f;
        }

#pragma unroll 2
        for (int it = 0; it < 16; ++it) {
            const f32x4 xv0 = *(const f32x4*)(xr0 + it * 32);
            const f32x4 xv1 = *(const f32x4*)(xr1 + it * 32);
            const f32x4 xv2 = *(const f32x4*)(xr2 + it * 32);
            const f32x4 xv3 = *(const f32x4*)(xr3 + it * 32);
#pragma unroll
            for (int o = 0; o < NOUT; ++o) {
                const f32x4 wv =
                    *(const f32x4*)&wlds[o * DD + it * 32 + d8 * 4];
                float a0 = acc0[o];
                float a1 = acc1[o];
                float a2 = acc2[o];
                float a3 = acc3[o];
                a0 = fmaf(xv0.x, wv.x, a0); a1 = fmaf(xv1.x, wv.x, a1);
                a2 = fmaf(xv2.x, wv.x, a2); a3 = fmaf(xv3.x, wv.x, a3);
                a0 = fmaf(xv0.y, wv.y, a0); a1 = fmaf(xv1.y, wv.y, a1);
                a2 = fmaf(xv2.y, wv.y, a2); a3 = fmaf(xv3.y, wv.y, a3);
                a0 = fmaf(xv0.z, wv.z, a0); a1 = fmaf(xv1.z, wv.z, a1);
                a2 = fmaf(xv2.z, wv.z, a2); a3 = fmaf(xv3.z, wv.z, a3);
                a0 = fmaf(xv0.w, wv.w, a0); a1 = fmaf(xv1.w, wv.w, a1);
                a2 = fmaf(xv2.w, wv.w, a2); a3 = fmaf(xv3.w, wv.w, a3);
                acc0[o] = a0;
                acc1[o] = a1;
                acc2[o] = a2;
                acc3[o] = a3;
            }
        }

        // Reduce partials across the 8-lane d-slice group (xor 1,2,4).
#pragma unroll
        for (int o = 0; o < NOUT; ++o) {
            float v0 = acc0[o];
            v0 += __shfl_xor(v0, 1); v0 += __shfl_xor(v0, 2); v0 += __shfl_xor(v0, 4);
            acc0[o] = v0;
            float v1 = acc1[o];
            v1 += __shfl_xor(v1, 1); v1 += __shfl_xor(v1, 2); v1 += __shfl_xor(v1, 4);
            acc1[o] = v1;
            float v2 = acc2[o];
            v2 += __shfl_xor(v2, 1); v2 += __shfl_xor(v2, 2); v2 += __shfl_xor(v2, 4);
            acc2[o] = v2;
            float v3 = acc3[o];
            v3 += __shfl_xor(v3, 1); v3 += __shfl_xor(v3, 2); v3 += __shfl_xor(v3, 4);
            acc3[o] = v3;
        }

        // ---- epilogue for the 4 tokens (proven path; d8==0 writes) ----
#pragma unroll
        for (int tk = 0; tk < 4; ++tk) {
            const float* acc = (tk == 0) ? acc0 : (tk == 1) ? acc1
                             : (tk == 2) ? acc2 : acc3;   // unroll-const select
            const int t = t0 + tk * 8;

            float gl[NG];
#pragma unroll
            for (int g = 0; g < NG; ++g) gl[g] = acc[g] + group_b[g];
            int bg = 0;
            float bv = gl[0];
#pragma unroll
            for (int g = 1; g < NG; ++g)
                if (gl[g] > bv) { bv = gl[g]; bg = g; }

            float il[NGS];
#pragma unroll
            for (int k = 0; k < NGS; ++k) il[k] = 0.f;
#pragma unroll
            for (int g = 0; g < NG; ++g) {
                const bool sel = (g == bg);
#pragma unroll
                for (int k = 0; k < NGS; ++k)
                    il[k] = sel ? acc[NG + g * NGS + k] : il[k];
            }
#pragma unroll
            for (int k = 0; k < NGS; ++k) il[k] += in_b[bg * NGS + k];

            float m = fmaxf(fmaxf(il[0], il[1]), fmaxf(il[2], il[3]));
            float pr[NGS];
            float s = 0.f;
#pragma unroll
            for (int k = 0; k < NGS; ++k) { pr[k] = expf(il[k] - m); s += pr[k]; }
            const float inv = 1.0f / s;
#pragma unroll
            for (int k = 0; k < NGS; ++k) pr[k] *= inv;

            int i1 = 0;
            float v1 = pr[0];
#pragma unroll
            for (int k = 1; k < NGS; ++k)
                if (pr[k] > v1) { v1 = pr[k]; i1 = k; }
            int i2 = -1;
            float v2 = -3.0e38f;
#pragma unroll
            for (int k = 0; k < NGS; ++k)
                if (k != i1 && pr[k] > v2) { v2 = pr[k]; i2 = k; }

            if (d8 == 0) {
                const int id1 = experts[bg * NGS + i1];
                const int id2 = experts[bg * NGS + i2];
                outi[t] = make_float2((float)id1, (float)id2);
                outw[t] = make_float2(v1, v2);
            }
        }
    }
}

extern "C" void kernel_launch(void* const* d_in, const int* in_sizes, int n_in,
                              void* d_out, int out_size, void* d_ws, size_t ws_size,
                              hipStream_t stream) {
    const float* x  = (const float*)d_in[0];
    const float* gw = (const float*)d_in[1];
    const float* gb = (const float*)d_in[2];
    const float* iw = (const float*)d_in[3];
    const float* ib = (const float*)d_in[4];
    const int*   et = (const int*)d_in[5];
    float* out = (float*)d_out;

    router_k<<<dim3(NB / TOKS), dim3(TPB), 0, stream>>>(x, gw, gb, iw, ib, et, out);
}

// Round 19
// 135.163 us; speedup vs baseline: 1.0795x; 1.0795x over previous
//
#include <hip/hip_runtime.h>
#include <math.h>

#define NB     262144   // batch (tokens)
#define DD     512      // d_routing
#define NG     4        // groups
#define NGS    4        // group size
#define NOUT   20       // 4 group logits + 16 in-group logits

#define TPB    256      // 4 waves/block; 40KB LDS -> 4 blocks/CU = 16 waves
#define TOKS   256      // tokens per block; wave owns 64 = 4 passes x 16

typedef float f32x4 __attribute__((ext_vector_type(4)));

// R17 (best: 142.7us) + nontemporal x loads. x is strictly single-touch
// (each full 128B line consumed exactly once by the loading instruction),
// so NT (no-allocate / streaming hint through L1+L2) cannot lose reuse --
// it only reduces cache-allocation overhead on the 512MB pure-read stream.
// Single-variable probe: everything else is R17 verbatim.
__global__ __launch_bounds__(TPB, 2) void router_k(
    const float* __restrict__ x,        // [NB, DD]
    const float* __restrict__ group_w,  // [NG, DD]
    const float* __restrict__ group_b,  // [NG]
    const float* __restrict__ in_w,     // [NG*NGS, DD]
    const float* __restrict__ in_b,     // [NG, NGS]
    const int*   __restrict__ experts,  // [NG, NGS]
    float*       __restrict__ out)      // [2*NB*2]: indices then weights, fp32
{
    __shared__ float wlds[NOUT * DD];   // 40960B: rows 0..3 gw, 4..19 in_w
    {
        const float4* gw4 = reinterpret_cast<const float4*>(group_w);
        const float4* iw4 = reinterpret_cast<const float4*>(in_w);
        float4* wl4 = reinterpret_cast<float4*>(wlds);
        for (int i = threadIdx.x; i < (NG * DD) / 4; i += TPB)
            wl4[i] = gw4[i];
        for (int i = threadIdx.x; i < (NG * NGS * DD) / 4; i += TPB)
            wl4[(NG * DD) / 4 + i] = iw4[i];
    }
    __syncthreads();   // only barrier in the kernel

    const int tid  = threadIdx.x;
    const int wid  = tid >> 6;
    const int lane = tid & 63;
    const int tg   = lane >> 3;         // token-in-pass (0..7)
    const int d8   = lane & 7;          // d-slice owner (0..7)
    const int wtok0 = blockIdx.x * TOKS + wid * 64;

    float2* outi = reinterpret_cast<float2*>(out);
    float2* outw = reinterpret_cast<float2*>(out + (size_t)NB * 2);

#pragma unroll 1
    for (int p = 0; p < 4; ++p) {
        const int t0 = wtok0 + p * 16 + tg;      // second token: t0 + 8
        const float* xr0 = x + (size_t)t0 * DD + d8 * 4;
        const float* xr1 = xr0 + 8 * DD;

        float acc0[NOUT], acc1[NOUT];
#pragma unroll
        for (int o = 0; o < NOUT; ++o) { acc0[o] = 0.f; acc1[o] = 0.f; }

#pragma unroll 4
        for (int it = 0; it < 16; ++it) {
            const f32x4 xv0 = __builtin_nontemporal_load(
                reinterpret_cast<const f32x4*>(xr0 + it * 32));
            const f32x4 xv1 = __builtin_nontemporal_load(
                reinterpret_cast<const f32x4*>(xr1 + it * 32));
#pragma unroll
            for (int o = 0; o < NOUT; ++o) {
                const f32x4 wv =
                    *(const f32x4*)&wlds[o * DD + it * 32 + d8 * 4];
                float a0 = acc0[o];
                float a1 = acc1[o];
                a0 = fmaf(xv0.x, wv.x, a0); a1 = fmaf(xv1.x, wv.x, a1);
                a0 = fmaf(xv0.y, wv.y, a0); a1 = fmaf(xv1.y, wv.y, a1);
                a0 = fmaf(xv0.z, wv.z, a0); a1 = fmaf(xv1.z, wv.z, a1);
                a0 = fmaf(xv0.w, wv.w, a0); a1 = fmaf(xv1.w, wv.w, a1);
                acc0[o] = a0;
                acc1[o] = a1;
            }
        }

        // Reduce partials across the 8-lane d-slice group (xor 1,2,4).
#pragma unroll
        for (int o = 0; o < NOUT; ++o) {
            float v0 = acc0[o];
            v0 += __shfl_xor(v0, 1);
            v0 += __shfl_xor(v0, 2);
            v0 += __shfl_xor(v0, 4);
            acc0[o] = v0;
            float v1 = acc1[o];
            v1 += __shfl_xor(v1, 1);
            v1 += __shfl_xor(v1, 2);
            v1 += __shfl_xor(v1, 4);
            acc1[o] = v1;
        }

        // ---- epilogue for both tokens (proven path; d8==0 writes) ----
#pragma unroll
        for (int tk = 0; tk < 2; ++tk) {
            const float* acc = (tk == 0) ? acc0 : acc1;  // unroll-const select
            const int t = t0 + tk * 8;

            float gl[NG];
#pragma unroll
            for (int g = 0; g < NG; ++g) gl[g] = acc[g] + group_b[g];
            int bg = 0;
            float bv = gl[0];
#pragma unroll
            for (int g = 1; g < NG; ++g)
                if (gl[g] > bv) { bv = gl[g]; bg = g; }

            float il[NGS];
#pragma unroll
            for (int k = 0; k < NGS; ++k) il[k] = 0.f;
#pragma unroll
            for (int g = 0; g < NG; ++g) {
                const bool sel = (g == bg);
#pragma unroll
                for (int k = 0; k < NGS; ++k)
                    il[k] = sel ? acc[NG + g * NGS + k] : il[k];
            }
#pragma unroll
            for (int k = 0; k < NGS; ++k) il[k] += in_b[bg * NGS + k];

            float m = fmaxf(fmaxf(il[0], il[1]), fmaxf(il[2], il[3]));
            float pr[NGS];
            float s = 0.f;
#pragma unroll
            for (int k = 0; k < NGS; ++k) { pr[k] = expf(il[k] - m); s += pr[k]; }
            const float inv = 1.0f / s;
#pragma unroll
            for (int k = 0; k < NGS; ++k) pr[k] *= inv;

            int i1 = 0;
            float v1 = pr[0];
#pragma unroll
            for (int k = 1; k < NGS; ++k)
                if (pr[k] > v1) { v1 = pr[k]; i1 = k; }
            int i2 = -1;
            float v2 = -3.0e38f;
#pragma unroll
            for (int k = 0; k < NGS; ++k)
                if (k != i1 && pr[k] > v2) { v2 = pr[k]; i2 = k; }

            if (d8 == 0) {
                const int id1 = experts[bg * NGS + i1];
                const int id2 = experts[bg * NGS + i2];
                outi[t] = make_float2((float)id1, (float)id2);
                outw[t] = make_float2(v1, v2);
            }
        }
    }
}

extern "C" void kernel_launch(void* const* d_in, const int* in_sizes, int n_in,
                              void* d_out, int out_size, void* d_ws, size_t ws_size,
                              hipStream_t stream) {
    const float* x  = (const float*)d_in[0];
    const float* gw = (const float*)d_in[1];
    const float* gb = (const float*)d_in[2];
    const float* iw = (const float*)d_in[3];
    const float* ib = (const float*)d_in[4];
    const int*   et = (const int*)d_in[5];
    float* out = (float*)d_out;

    router_k<<<dim3(NB / TOKS), dim3(TPB), 0, stream>>>(x, gw, gb, iw, ib, et, out);
}